// Round 2
// baseline (658.234 us; speedup 1.0000x reference)
//
#include <hip/hip_runtime.h>

// PBKDF2 with toy HMAC (see reference). Fully serial chain -> single thread.
// All &255 masks deferred to the end: +, ^, *31 preserve low 8 bits mod 2^32.
// State: r[32] (current U), F[32] (xor accumulator), p31[16] = pw*31.
// All loops fully unrolled so arrays become registers.
// (Resubmission of round-0 kernel: round-1 bench died on container infra,
//  kernel itself was never measured.)

__global__ void __launch_bounds__(64) Model_62955630625117_kernel(
    const int* __restrict__ pw_g,
    const int* __restrict__ salt_g,
    int* __restrict__ out)
{
    unsigned pw[16], salt[16], p31[16];
    unsigned r[32], F[32];

    #pragma unroll
    for (int j = 0; j < 16; ++j) pw[j] = (unsigned)pw_g[j];
    #pragma unroll
    for (int j = 0; j < 16; ++j) salt[j] = (unsigned)salt_g[j];
    #pragma unroll
    for (int j = 0; j < 16; ++j) p31[j] = pw[j] * 31u;

    // ---- U0 = hmac(pw, salt || {0,0,0,1}) ----
    // absorb (combined len 36): closed form
    r[0] = p31[0];
    r[1] = p31[1];
    r[2] = p31[2];
    r[3] = p31[3] + 1u;
    #pragma unroll
    for (int j = 4; j < 16; ++j) r[j] = pw[j];
    #pragma unroll
    for (int j = 0; j < 16; ++j) r[16 + j] = salt[j];

    // mix: 4 rounds x 32 sequential in-place steps (mask deferred)
    #pragma unroll
    for (int rd = 0; rd < 4; ++rd) {
        #pragma unroll
        for (int i = 0; i < 32; ++i) {
            r[i] ^= r[(i + 17) & 31] + r[(i + 11) & 31];
        }
    }

    #pragma unroll
    for (int j = 0; j < 32; ++j) F[j] = r[j];

    // ---- 999 chained iterations: U = hmac(pw, U); F ^= U ----
    #pragma unroll 2
    for (int it = 0; it < 999; ++it) {
        // absorb (combined = pw(16) || U(32)):
        //   new r[j]    = p31[j] + U[j+16]   (j in 0..15)
        //   new r[j+16] = U[j]
        #pragma unroll
        for (int j = 0; j < 16; ++j) {
            unsigned t = r[j];
            r[j] = p31[j] + r[j + 16];
            r[j + 16] = t;
        }
        // mix
        #pragma unroll
        for (int rd = 0; rd < 4; ++rd) {
            #pragma unroll
            for (int i = 0; i < 32; ++i) {
                r[i] ^= r[(i + 17) & 31] + r[(i + 11) & 31];
            }
        }
        // accumulate
        #pragma unroll
        for (int j = 0; j < 32; ++j) F[j] ^= r[j];
    }

    if (threadIdx.x == 0 && blockIdx.x == 0) {
        #pragma unroll
        for (int j = 0; j < 32; ++j) out[j] = (int)(F[j] & 255u);
    }
}

extern "C" void kernel_launch(void* const* d_in, const int* in_sizes, int n_in,
                              void* d_out, int out_size, void* d_ws, size_t ws_size,
                              hipStream_t stream) {
    const int* pw   = (const int*)d_in[0];
    const int* salt = (const int*)d_in[1];
    int* out = (int*)d_out;
    Model_62955630625117_kernel<<<1, 64, 0, stream>>>(pw, salt, out);
}

// Round 5
// 310.661 us; speedup vs baseline: 2.1188x; 2.1188x over previous
//
#include <hip/hip_runtime.h>

// PBKDF2 toy-HMAC, lane-parallel. Round-5 fix: v_permlane32_swap_b32 moved
// from inline asm to __builtin_amdgcn_permlane32_swap. Inline asm bypasses
// LLVM's hazard recognizer; gfx950 requires wait-states around permlane_swap
// adjacent to VALU writes, so the asm version read stale lanes (rounds 3-4
// failed with scrambled-but-deterministic output). The builtin is hazard-safe.
//
// Layout: lane L = (row = L>>4, s = L&15); byte B = s for rows 0,3 and 16+s
// for rows 1,2  =>  byte((B+16)%32) lives at lane L^32 (permlane32_swap),
// bytes contiguous in s within each row (DPP row rotates).
// Mix round = 3 dependency levels: bytes {0-14 | 15-29 | 30-31} (verified:
// within a level all operand reads are sequentially-older positions).
// permlane32_swap(r,r) returns res.x/res.y holding {swapped, original} in
// complementary halves; gather inputs are ONE cndmask off res:
//   g17: dst s <- src (s+1)&15 of  t17 = (src s==0   ? r : sw)
//   g11: dst s <- src (s-5)&15 of  t11 = (src s>=11  ? r : sw)
// Orientation (bx) and DPP rotate direction are runtime-probed, folded into
// loop-invariant per-lane masks. All &255 deferred to the end (+, ^, *31
// preserve low 8 bits mod 2^32).

typedef int iv2 __attribute__((ext_vector_type(2)));

template<bool FLIP>
__device__ __forceinline__ unsigned run_chain(unsigned r, unsigned p31v,
                                              bool takeX, bool sel17, bool sel11,
                                              bool L1m, bool L2m, bool L3m)
{
    // want P1: dst s <- src (s+1)&15 ; M5: dst s <- src (s-5)&15
    // primary semantics: row_ror:N => dst s <- src (s-N)&15  -> 0x12F / 0x125
    // flipped semantics: row_ror:N => dst s <- src (s+N)&15  -> 0x121 / 0x12B
    constexpr int CTRL_P1 = FLIP ? 0x121 : 0x12F;
    constexpr int CTRL_M5 = FLIP ? 0x12B : 0x125;

#define LEVEL(Lm)                                                                                \
    {   iv2 res_ = __builtin_amdgcn_permlane32_swap((int)r, (int)r, false, false);               \
        unsigned x_ = (unsigned)res_[0], y_ = (unsigned)res_[1];                                 \
        unsigned t17_ = sel17 ? x_ : y_;                                                         \
        unsigned t11_ = sel11 ? x_ : y_;                                                         \
        unsigned g17_ = (unsigned)__builtin_amdgcn_mov_dpp((int)t17_, CTRL_P1, 0xF, 0xF, false); \
        unsigned g11_ = (unsigned)__builtin_amdgcn_mov_dpp((int)t11_, CTRL_M5, 0xF, 0xF, false); \
        unsigned nv_ = r ^ (g17_ + g11_);                                                        \
        r = (Lm) ? nv_ : r; }

#define MIXROUND { LEVEL(L1m); LEVEL(L2m); LEVEL(L3m); }

    // U0 mix
    MIXROUND; MIXROUND; MIXROUND; MIXROUND;

    unsigned F = r;

    #pragma unroll 1
    for (int it = 0; it < 999; ++it) {
        // absorb: new byte B = old byte((B+16)%32) + p31v  (p31v = pw[B]*31, 0 for B>=16)
        {
            iv2 res_ = __builtin_amdgcn_permlane32_swap((int)r, (int)r, false, false);
            unsigned sw_ = takeX ? (unsigned)res_[0] : (unsigned)res_[1];
            r = sw_ + p31v;
        }
        MIXROUND; MIXROUND; MIXROUND; MIXROUND;
        F ^= r;
    }
    return F;

#undef MIXROUND
#undef LEVEL
}

__global__ void __launch_bounds__(64) Model_62955630625117_kernel(
    const int* __restrict__ pw_g,
    const int* __restrict__ salt_g,
    int* __restrict__ out)
{
    const int lane = (int)threadIdx.x;
    const unsigned row = (unsigned)(lane >> 4) & 3u;
    const unsigned s   = (unsigned)(lane & 15);
    // byte index held by this lane: rows 0,3 -> s ; rows 1,2 -> 16+s
    const unsigned B = ((row == 1u || row == 2u) ? 16u : 0u) + s;
    const bool halfHi = (lane >= 32);
    const bool m_s0   = (s == 0u);
    const bool m_ge11 = (s >= 11u);
    const bool L1m = (B <= 14u);
    const bool L2m = (B >= 15u) & (B <= 29u);
    const bool L3m = (B >= 30u);

    // --- probe permlane32_swap orientation ---
    // Expected: res.x = lanes 0-31 swapped-in (x[0] = 32). Other orientation: x[0] = 0.
    iv2 pr = __builtin_amdgcn_permlane32_swap(lane, lane, false, false);
    const bool bx = (__builtin_amdgcn_readfirstlane(pr[0]) != 0); // x carries swapped LOW half
    // takeX: which output holds the swapped value for THIS lane
    const bool takeX = ((!halfHi) == bx);
    // gather pre-select folded with orientation: choose x when (halfHi == wantR) == bx
    const bool sel17 = ((halfHi == m_s0)   == bx);
    const bool sel11 = ((halfHi == m_ge11) == bx);

    // --- probe DPP row_ror direction ---
    // primary: row_ror:15 => dst s <- src (s+1)&15 => lane0 receives 1
    int q = __builtin_amdgcn_mov_dpp(lane, 0x12F, 0xF, 0xF, false);
    const bool dppflip = (__builtin_amdgcn_readfirstlane(q) != 1);

    // per-lane constants
    const unsigned p31v = (B < 16u) ? (unsigned)pw_g[B] * 31u : 0u;

    // --- initial state: U0 absorb closed form (pw || salt || {0,0,0,1}) ---
    unsigned r;
    if (B < 4u)       r = (unsigned)pw_g[B] * 31u + (B == 3u ? 1u : 0u);
    else if (B < 16u) r = (unsigned)pw_g[B];
    else              r = (unsigned)salt_g[B - 16u];

    unsigned F = dppflip
        ? run_chain<true >(r, p31v, takeX, sel17, sel11, L1m, L2m, L3m)
        : run_chain<false>(r, p31v, takeX, sel17, sel11, L1m, L2m, L3m);

    if (lane < 32) out[lane] = (int)(F & 255u);
}

extern "C" void kernel_launch(void* const* d_in, const int* in_sizes, int n_in,
                              void* d_out, int out_size, void* d_ws, size_t ws_size,
                              hipStream_t stream) {
    const int* pw   = (const int*)d_in[0];
    const int* salt = (const int*)d_in[1];
    int* out = (int*)d_out;
    Model_62955630625117_kernel<<<1, 64, 0, stream>>>(pw, salt, out);
}

// Round 6
// 189.260 us; speedup vs baseline: 3.4779x; 1.6415x over previous
//
#include <hip/hip_runtime.h>

// PBKDF2 toy-HMAC, lane-parallel, round-6: two-register layout kills the swap.
//
// State in (u,v) across 16 lanes (replicated in all four 16-lane rows):
//   u[s] = byte s,  v[s] = byte 16+s   (s = lane & 15)
// => absorb (new[j] = pw[j]*31 + old[j+16]; new[j+16] = old[j]) is
//    u' = v + p31 ; v' = u   -- ONE add + rename, no lane movement.
// Gathers are row-local DPP rotates:
//   D1 (w)[s] = w[(s+1)&15]   ("+17" component)
//   D11(w)[s] = w[(s+11)&15]  ("+11" component)
// Mix round = 3 dependency levels (bytes {0-14 | 15-29 | 30-31}), derived in
// (u,v) coords with per-position freshness checks:
//   L1 (u, s<=14): u ^= D1(v) + (s<=4 ? D11(u) : D11(v))
//   L2 (u@15, v@s<=13): sum = D1(u1) + ((s<=4||s==15) ? D11(v_old) : D11(u1))
//        u@15 ^= sum ; v@s<=13 ^= sum       (one shared sum)
//   L3 (v, s>=14): v ^= (s==15 ? D1(v2) : D1(u2)) + D11(u1)
//        (D11(u1) reused from L2: stale only at dst s==4, unused in L3)
// DPP reuse: Bv = D11(v) computed in L1 serves L2 (v untouched in L1).
// DPP rotate direction runtime-probed (uniform branch, zero per-iter cost).
// All &255 deferred to the end: +, ^, *31 preserve low 8 bits mod 2^32.

template<bool FLIP>
__device__ __forceinline__ void run_chain(unsigned &u, unsigned &v,
                                          unsigned &Fu, unsigned &Fv,
                                          unsigned p31v,
                                          bool m_le4, bool m_le13, bool m_le14,
                                          bool m_s15, bool m_ge14, bool m_l2)
{
    // primary semantics: row_ror:N => dst s <- src (s-N)&15
    //   D1 : want dst<-src(s+1)  => N=15 -> 0x12F ; flipped -> 0x121
    //   D11: want dst<-src(s+11) => N=5  -> 0x125 ; flipped -> 0x12B
    constexpr int P1  = FLIP ? 0x121 : 0x12F;
    constexpr int P11 = FLIP ? 0x12B : 0x125;

#define D1(w)  ((unsigned)__builtin_amdgcn_mov_dpp((int)(w), P1,  0xF, 0xF, false))
#define D11(w) ((unsigned)__builtin_amdgcn_mov_dpp((int)(w), P11, 0xF, 0xF, false))

#define MIXROUND                                                   \
  { /* L1: update u at s<=14 */                                    \
    unsigned Bv  = D11(v);                                         \
    unsigned Bu1 = D11(u);                                         \
    unsigned A1  = D1(v);                                          \
    unsigned g11a = m_le4 ? Bu1 : Bv;                              \
    unsigned nu1 = u ^ (A1 + g11a);                                \
    u = m_le14 ? nu1 : u;                                          \
    /* L2: update u at s==15 and v at s<=13 (shared sum) */        \
    unsigned A2  = D1(u);                                          \
    unsigned Bu2 = D11(u);                                         \
    unsigned g11b = m_l2 ? Bv : Bu2;                               \
    unsigned sum2 = A2 + g11b;                                     \
    unsigned nu2 = u ^ sum2;                                       \
    unsigned nv2 = v ^ sum2;                                       \
    u = m_s15 ? nu2 : u;                                           \
    v = m_le13 ? nv2 : v;                                          \
    /* L3: update v at s>=14 (Bu2 reused: stale only at dst s==4) */ \
    unsigned Au = D1(u);                                           \
    unsigned Av = D1(v);                                           \
    unsigned g17c = m_s15 ? Av : Au;                               \
    unsigned nv3 = v ^ (g17c + Bu2);                               \
    v = m_ge14 ? nv3 : v;                                          \
  }

    // U0 mix (4 rounds)
    MIXROUND; MIXROUND; MIXROUND; MIXROUND;

    Fu = u; Fv = v;

    #pragma unroll 1
    for (int it = 0; it < 999; ++it) {
        // absorb: u' = v + p31 ; v' = u
        unsigned nu = v + p31v;
        v = u;
        u = nu;
        MIXROUND; MIXROUND; MIXROUND; MIXROUND;
        Fu ^= u;
        Fv ^= v;
    }

#undef MIXROUND
#undef D11
#undef D1
}

__global__ void __launch_bounds__(64) Model_62955630625117_kernel(
    const int* __restrict__ pw_g,
    const int* __restrict__ salt_g,
    int* __restrict__ out)
{
    const int lane = (int)threadIdx.x;
    const unsigned s = (unsigned)(lane & 15);

    // loop-invariant lane masks
    const bool m_le4  = (s <= 4u);
    const bool m_le13 = (s <= 13u);
    const bool m_le14 = (s <= 14u);
    const bool m_s15  = (s == 15u);
    const bool m_ge14 = (s >= 14u);
    const bool m_l2   = (s <= 4u) || (s == 15u);

    // --- probe DPP row_ror direction ---
    // primary: 0x12F => dst s <- src (s+1)&15 => lane0 receives 1
    int q = __builtin_amdgcn_mov_dpp((int)s, 0x12F, 0xF, 0xF, false);
    const bool dppflip = (__builtin_amdgcn_readfirstlane(q) != 1);

    // per-lane constants (same in every row)
    const unsigned pwv  = (unsigned)pw_g[s];
    const unsigned p31v = pwv * 31u;

    // --- initial state: U0 absorb closed form (pw || salt || {0,0,0,1}) ---
    unsigned u = (s < 4u) ? (p31v + (s == 3u ? 1u : 0u)) : pwv;
    unsigned v = (unsigned)salt_g[s];

    unsigned Fu, Fv;
    if (dppflip) run_chain<true >(u, v, Fu, Fv, p31v, m_le4, m_le13, m_le14, m_s15, m_ge14, m_l2);
    else         run_chain<false>(u, v, Fu, Fv, p31v, m_le4, m_le13, m_le14, m_s15, m_ge14, m_l2);

    if (lane < 32) out[lane] = (int)((lane < 16 ? Fu : Fv) & 255u);
}

extern "C" void kernel_launch(void* const* d_in, const int* in_sizes, int n_in,
                              void* d_out, int out_size, void* d_ws, size_t ws_size,
                              hipStream_t stream) {
    const int* pw   = (const int*)d_in[0];
    const int* salt = (const int*)d_in[1];
    int* out = (int*)d_out;
    Model_62955630625117_kernel<<<1, 64, 0, stream>>>(pw, salt, out);
}

// Round 7
// 156.044 us; speedup vs baseline: 4.2183x; 1.2129x over previous
//
#include <hip/hip_runtime.h>

// PBKDF2 toy-HMAC, lane-parallel (u,v) layout, round-7: fused merges.
//
// State across 16 lanes (replicated in all four row-groups):
//   u[s] = byte s,  v[s] = byte 16+s   (s = lane & 15)
// absorb: u' = v + p31 ; v' = u  (1 add + renames; unroll-2 makes renames free)
// Gathers: D1(w)[s] = w[(s+1)&15], D11(w)[s] = w[(s+11)&15]  (DPP row_ror).
//
// Mix round (for i=0..31: r[i] ^= r[(i+17)%32] + r[(i+11)%32], masks deferred)
// in 3 levels with FUSED merges — operands proven valid from UNMERGED values:
//  L1 (bytes 0-14):  nu1 = u ^ (D1(v) + (s<=4 ? D11(u) : D11(v)))
//      [byte s: +17 -> byte 16+(s+1) old = D1(v) ; +11 -> s<=4: byte s+11 old-u,
//       s>=5: byte 16+(s-5) old-v]
//  L2 (byte 15, bytes 16-29): A2 = D1(nu1)  [dst15<-src0 fresh; dst s<=13 <- src s+1
//       fresh; dst14 <- src15 garbage but UNCONSUMED]
//      Bu2 = D11(nu1) [consumed at dst 5..13 (src 0..8 fresh) and dst 14,15
//       (src 9,10 fresh) -- shared with L3]
//      g11b = (s<=4 || s==15) ? D11(v_old) : Bu2   [bytes 27+s / 26 old-v]
//      sum2 = A2 + g11b ; nu2 = u ^ sum2 ; nv2 = v ^ sum2
//      u_final = (s<=14) ? nu1 : nu2            <- ONE merge for u
//  L3 (bytes 30,31): Au = D1(nu2) [only dst14<-src15 consumed, valid]
//      Av = D1(nv2)  [only dst15<-src0 consumed, valid]
//      nv3 = v ^ ((s==15 ? Av : Au) + Bu2)   [+11: bytes 9,10 = src 9,10 of Bu2]
//      v_final = (s<=13) ? nv2 : nv3            <- ONE merge for v
// 19 instrs/round, depth ~13; merges off the operand path.
// DPP rotate direction runtime-probed (uniform branch, zero per-iter cost).
// All &255 deferred to the end: +, ^, *31 preserve low 8 bits mod 2^32.

template<bool FLIP>
__device__ __forceinline__ void run_chain(unsigned &u, unsigned &v,
                                          unsigned &Fu, unsigned &Fv,
                                          unsigned p31v,
                                          bool m_le4, bool m_le13, bool m_le14,
                                          bool m_s15, bool m_l2)
{
    // primary semantics: row_ror:N => dst s <- src (s-N)&15
    //   D1 : dst<-src(s+1)  => N=15 -> 0x12F ; flipped -> 0x121
    //   D11: dst<-src(s+11) => N=5  -> 0x125 ; flipped -> 0x12B
    constexpr int P1  = FLIP ? 0x121 : 0x12F;
    constexpr int P11 = FLIP ? 0x12B : 0x125;

#define D1(w)  ((unsigned)__builtin_amdgcn_mov_dpp((int)(w), P1,  0xF, 0xF, false))
#define D11(w) ((unsigned)__builtin_amdgcn_mov_dpp((int)(w), P11, 0xF, 0xF, false))

#define MIXROUND                                                   \
  { unsigned Bv  = D11(v);                                         \
    unsigned Bu1 = D11(u);                                         \
    unsigned A1  = D1(v);                                          \
    unsigned g11a = m_le4 ? Bu1 : Bv;                              \
    unsigned nu1 = u ^ (A1 + g11a);                                \
    unsigned A2  = D1(nu1);                                        \
    unsigned Bu2 = D11(nu1);                                       \
    unsigned g11b = m_l2 ? Bv : Bu2;                               \
    unsigned sum2 = A2 + g11b;                                     \
    unsigned nu2 = u ^ sum2;                                       \
    unsigned nv2 = v ^ sum2;                                       \
    u = m_le14 ? nu1 : nu2;                                        \
    unsigned Au = D1(nu2);                                         \
    unsigned Av = D1(nv2);                                         \
    unsigned g17c = m_s15 ? Av : Au;                               \
    unsigned nv3 = v ^ (g17c + Bu2);                               \
    v = m_le13 ? nv2 : nv3;                                        \
  }

    // U0 mix (4 rounds)
    MIXROUND; MIXROUND; MIXROUND; MIXROUND;

    Fu = u; Fv = v;

    #pragma unroll 2
    for (int it = 0; it < 999; ++it) {
        // absorb: u' = v + p31 ; v' = u
        unsigned nu = v + p31v;
        v = u;
        u = nu;
        MIXROUND; MIXROUND; MIXROUND; MIXROUND;
        Fu ^= u;
        Fv ^= v;
    }

#undef MIXROUND
#undef D11
#undef D1
}

__global__ void __launch_bounds__(64) Model_62955630625117_kernel(
    const int* __restrict__ pw_g,
    const int* __restrict__ salt_g,
    int* __restrict__ out)
{
    const int lane = (int)threadIdx.x;
    const unsigned s = (unsigned)(lane & 15);

    // loop-invariant lane masks
    const bool m_le4  = (s <= 4u);
    const bool m_le13 = (s <= 13u);
    const bool m_le14 = (s <= 14u);
    const bool m_s15  = (s == 15u);
    const bool m_l2   = (s <= 4u) || (s == 15u);

    // --- probe DPP row_ror direction ---
    // primary: 0x12F => dst s <- src (s+1)&15 => lane0 receives 1
    int q = __builtin_amdgcn_mov_dpp((int)s, 0x12F, 0xF, 0xF, false);
    const bool dppflip = (__builtin_amdgcn_readfirstlane(q) != 1);

    // per-lane constants (same in every 16-lane row)
    const unsigned pwv  = (unsigned)pw_g[s];
    const unsigned p31v = pwv * 31u;

    // --- initial state: U0 absorb closed form (pw || salt || {0,0,0,1}) ---
    unsigned u = (s < 4u) ? (p31v + (s == 3u ? 1u : 0u)) : pwv;
    unsigned v = (unsigned)salt_g[s];

    unsigned Fu, Fv;
    if (dppflip) run_chain<true >(u, v, Fu, Fv, p31v, m_le4, m_le13, m_le14, m_s15, m_l2);
    else         run_chain<false>(u, v, Fu, Fv, p31v, m_le4, m_le13, m_le14, m_s15, m_l2);

    if (lane < 32) out[lane] = (int)((lane < 16 ? Fu : Fv) & 255u);
}

extern "C" void kernel_launch(void* const* d_in, const int* in_sizes, int n_in,
                              void* d_out, int out_size, void* d_ws, size_t ws_size,
                              hipStream_t stream) {
    const int* pw   = (const int*)d_in[0];
    const int* salt = (const int*)d_in[1];
    int* out = (int*)d_out;
    Model_62955630625117_kernel<<<1, 64, 0, stream>>>(pw, salt, out);
}